// Round 6
// baseline (1150.427 us; speedup 1.0000x reference)
//
#include <hip/hip_runtime.h>
#include <hip/hip_bf16.h>

// ---------------------------------------------------------------------------
// GCNFN: 2x GATConv(heads=1) + SELU, global mean pool, MLP head, log_softmax
// N=100000 nodes, E=1600000 canonical edges (expanded to 2E directed + N self)
//
// R1: lo-side adjacency from sorted edge list (binary search); hi-side CSR.
// R2: bf16 shadow of h for the agg gather (halves gather bytes).
// R3: pool_mlp 1024-thread parallel reduction (was 2.6% occupancy).
// R4: bf16 MFMA GEMM (16x16x32, fp32 accum) replaces fp32 VALU SGEMM.
// R5: scatter (130us, 103MB WRITE = 16x line amplification) -> two-pass
//     bucketed scatter: binA appends (u,v) to v>>7 bucket (sequential line
//     fill), binB places within bucket's ~8KB CSR span (L2-resident).
//     agg gather unroll 4 -> 8 (probe: latency- vs IC-BW-bound).
// ---------------------------------------------------------------------------

#define NN 100000
#define EE 1600000
#define GG 128
#define HID 128
#define AGG_CAP 512
#define NEG_SLOPE 0.2f
#define BKT_SHIFT 7
#define NBKT ((NN + 127) >> 7)   // 782

typedef short bf16x8 __attribute__((ext_vector_type(8)));
typedef float f32x4 __attribute__((ext_vector_type(4)));

__device__ __forceinline__ float lrelu(float x) { return x > 0.f ? x : NEG_SLOPE * x; }

__device__ __forceinline__ float selu(float x) {
    const float sc = 1.0507009873554805f, al = 1.6732632423543772f;
    return x > 0.f ? sc * x : sc * al * (__expf(x) - 1.f);
}

__device__ __forceinline__ unsigned short f2bf(float x) {
    unsigned int b = __float_as_uint(x);
    b += 0x7FFFu + ((b >> 16) & 1u);          // round-to-nearest-even
    return (unsigned short)(b >> 16);
}

// ---------------- fp32 -> bf16 cast (weights) ----------------

__global__ __launch_bounds__(256) void castbf_kernel(const float* __restrict__ in,
                                                     unsigned short* __restrict__ out, int n) {
    int i = (blockIdx.x * blockDim.x + threadIdx.x) * 4;
    if (i >= n) return;
    float4 v = *reinterpret_cast<const float4*>(in + i);
    union { unsigned short u[4]; uint2 w; } pk;
    pk.u[0] = f2bf(v.x); pk.u[1] = f2bf(v.y); pk.u[2] = f2bf(v.z); pk.u[3] = f2bf(v.w);
    *reinterpret_cast<uint2*>(out + i) = pk.w;
}

// ---------------- lo-side row starts: binary search over sorted lo column ----

__global__ __launch_bounds__(256) void loptr_kernel(const int* __restrict__ ei,
                                                    int* __restrict__ loptr, int n, int E_) {
    int v = blockIdx.x * blockDim.x + threadIdx.x;
    if (v > n) return;
    int lo = 0, hi = E_;
    while (lo < hi) {
        int mid = (lo + hi) >> 1;
        if (ei[mid] < v) lo = mid + 1; else hi = mid;
    }
    loptr[v] = lo;
}

// ---------------- hi-side CSR build ----------------

__global__ void count_kernel(const int* __restrict__ ei, int* __restrict__ deg, int E_) {
    int e = blockIdx.x * blockDim.x + threadIdx.x;
    if (e >= E_) return;
    atomicAdd(&deg[ei[E_ + e]], 1);   // hi endpoint only
}

#define SCAN_CHUNK 512

__global__ __launch_bounds__(256) void block_sum_kernel(const int* __restrict__ deg,
                                                        int* __restrict__ bsum, int n) {
    __shared__ int sd[256];
    int b = blockIdx.x, t = threadIdx.x;
    int base = b * SCAN_CHUNK;
    int v = 0;
    int i0 = base + t, i1 = base + t + 256;
    if (i0 < n) v += deg[i0];
    if (i1 < n) v += deg[i1];
    sd[t] = v;
    __syncthreads();
    for (int off = 128; off; off >>= 1) {
        if (t < off) sd[t] += sd[t + off];
        __syncthreads();
    }
    if (t == 0) bsum[b] = sd[0];
}

__global__ __launch_bounds__(256) void top_scan_kernel(const int* __restrict__ bsum,
                                                       int* __restrict__ boff, int nb,
                                                       int* __restrict__ total_out) {
    __shared__ int a[256], b[256];
    int t = threadIdx.x;
    int v = (t < nb) ? bsum[t] : 0;
    int* cur = a; int* nxt = b;
    cur[t] = v;
    __syncthreads();
    for (int off = 1; off < 256; off <<= 1) {
        int val = cur[t] + ((t >= off) ? cur[t - off] : 0);
        nxt[t] = val;
        __syncthreads();
        int* tmp = cur; cur = nxt; nxt = tmp;
    }
    if (t < nb) boff[t] = cur[t] - v;            // exclusive offset per block
    if (t == nb - 1) *total_out = cur[t];        // row_ptr[N] = E
}

__global__ __launch_bounds__(512) void scan_final_kernel(const int* __restrict__ deg,
                                                         const int* __restrict__ boff,
                                                         int* __restrict__ row_ptr,
                                                         int* __restrict__ cursor, int n) {
    __shared__ int a[512], b[512];
    int blk = blockIdx.x, t = threadIdx.x;
    int i = blk * 512 + t;
    int v = (i < n) ? deg[i] : 0;
    int orig = v;
    int* cur = a; int* nxt = b;
    cur[t] = v;
    __syncthreads();
    for (int off = 1; off < 512; off <<= 1) {
        int val = cur[t] + ((t >= off) ? cur[t - off] : 0);
        nxt[t] = val;
        __syncthreads();
        int* tmp = cur; cur = nxt; nxt = tmp;
    }
    if (i < n) {
        int excl = cur[t] - orig + boff[blk];
        row_ptr[i] = excl;
        cursor[i] = excl;
    }
}

// ---- two-pass bucketed scatter (R5) ----

__global__ __launch_bounds__(256) void bcur_init_kernel(const int* __restrict__ row_ptr,
                                                        int* __restrict__ bcur) {
    int b = blockIdx.x * blockDim.x + threadIdx.x;
    if (b < NBKT) bcur[b] = row_ptr[b << BKT_SHIFT];
}

__global__ __launch_bounds__(256) void binA_kernel(const int* __restrict__ ei,
                                                   int* __restrict__ bcur,
                                                   uint2* __restrict__ tmp, int E_) {
    int e = blockIdx.x * blockDim.x + threadIdx.x;
    if (e >= E_) return;
    int u = ei[e], v = ei[E_ + e];
    int b = v >> BKT_SHIFT;
    int p = atomicAdd(&bcur[b], 1);          // bucket tail: sequential line fill
    tmp[p] = make_uint2((unsigned)u, (unsigned)v);
}

__global__ __launch_bounds__(256) void binB_kernel(const uint2* __restrict__ tmp,
                                                   int* __restrict__ cursor,
                                                   int* __restrict__ csr, int E_) {
    int i = blockIdx.x * blockDim.x + threadIdx.x;
    if (i >= E_) return;
    uint2 t = tmp[i];
    int p = atomicAdd(&cursor[t.y], 1);      // final pos within bucket's ~8KB span
    csr[p] = (int)t.x;
}

// ---------------- MFMA GEMM: C[M][128] = A[M][K] @ W[128][K]^T ----------------
// BM=128, BN=128, BK=32; 256 threads = 4 waves (2x2), each wave 64x64 out.

template<int K, bool BF16IN>
__global__ __launch_bounds__(256) void mfma_gemm(const void* __restrict__ Ain,
                                                 const unsigned short* __restrict__ Wb,
                                                 float* __restrict__ C,
                                                 unsigned short* __restrict__ Cb,
                                                 int M) {
    __shared__ unsigned short As[128 * 32];
    __shared__ unsigned short Bs[128 * 32];
    int tid = threadIdx.x;
    int brow = blockIdx.x * 128;
    int w = tid >> 6, lane = tid & 63;
    int wr = (w >> 1) * 64, wc = (w & 1) * 64;
    int l15 = lane & 15, g = lane >> 4;

    const f32x4 zero = {0.f, 0.f, 0.f, 0.f};
    f32x4 acc[4][4];
    #pragma unroll
    for (int m = 0; m < 4; ++m)
        #pragma unroll
        for (int n = 0; n < 4; ++n) acc[m][n] = zero;

    int srow = tid >> 2;        // 0..63
    int slot = tid & 3;         // 16B slot within 64B row

    for (int k0 = 0; k0 < K; k0 += 32) {
        #pragma unroll
        for (int half = 0; half < 2; ++half) {
            int r = srow + half * 64;
            int grow = brow + r;
            union { unsigned short u[8]; uint4 v; } pk;
            if (BF16IN) {
                const unsigned short* A16 = (const unsigned short*)Ain;
                if (grow < M)
                    pk.v = *reinterpret_cast<const uint4*>(A16 + (size_t)grow * K + k0 + slot * 8);
                else pk.v = make_uint4(0, 0, 0, 0);
            } else {
                const float* A32 = (const float*)Ain;
                if (grow < M) {
                    const float4* p = reinterpret_cast<const float4*>(A32 + (size_t)grow * K + k0 + slot * 8);
                    float4 f0 = p[0], f1 = p[1];
                    pk.u[0] = f2bf(f0.x); pk.u[1] = f2bf(f0.y);
                    pk.u[2] = f2bf(f0.z); pk.u[3] = f2bf(f0.w);
                    pk.u[4] = f2bf(f1.x); pk.u[5] = f2bf(f1.y);
                    pk.u[6] = f2bf(f1.z); pk.u[7] = f2bf(f1.w);
                } else pk.v = make_uint4(0, 0, 0, 0);
            }
            int ss = slot ^ (r & 3);
            *reinterpret_cast<uint4*>(&As[r * 32 + ss * 8]) = pk.v;
        }
        #pragma unroll
        for (int half = 0; half < 2; ++half) {
            int r = srow + half * 64;
            uint4 v = *reinterpret_cast<const uint4*>(Wb + (size_t)r * K + k0 + slot * 8);
            int ss = slot ^ (r & 3);
            *reinterpret_cast<uint4*>(&Bs[r * 32 + ss * 8]) = v;
        }
        __syncthreads();

        bf16x8 af[4], bfr[4];
        #pragma unroll
        for (int m = 0; m < 4; ++m) {
            int row = wr + m * 16 + l15;
            af[m] = *reinterpret_cast<const bf16x8*>(&As[row * 32 + ((g ^ (row & 3)) * 8)]);
        }
        #pragma unroll
        for (int n = 0; n < 4; ++n) {
            int col = wc + n * 16 + l15;
            bfr[n] = *reinterpret_cast<const bf16x8*>(&Bs[col * 32 + ((g ^ (col & 3)) * 8)]);
        }
        #pragma unroll
        for (int m = 0; m < 4; ++m)
            #pragma unroll
            for (int n = 0; n < 4; ++n)
                acc[m][n] = __builtin_amdgcn_mfma_f32_16x16x32_bf16(af[m], bfr[n], acc[m][n], 0, 0, 0);
        __syncthreads();
    }

    #pragma unroll
    for (int m = 0; m < 4; ++m) {
        int rbase = brow + wr + m * 16 + g * 4;
        #pragma unroll
        for (int j = 0; j < 4; ++j) {
            int row = rbase + j;
            if (row < M) {
                #pragma unroll
                for (int n = 0; n < 4; ++n) {
                    int col = wc + n * 16 + l15;
                    float val = acc[m][n][j];
                    C[(size_t)row * 128 + col] = val;
                    Cb[(size_t)row * 128 + col] = f2bf(val);
                }
            }
        }
    }
}

// ---------------- per-node attention dot products ----------------

__global__ __launch_bounds__(256) void hshd_kernel(const float* __restrict__ h,
                                                   const float* __restrict__ a_src,
                                                   const float* __restrict__ a_dst,
                                                   float* __restrict__ hs, float* __restrict__ hd,
                                                   int n) {
    int w = (blockIdx.x * blockDim.x + threadIdx.x) >> 6;
    int lane = threadIdx.x & 63;
    if (w >= n) return;
    float2 hv = reinterpret_cast<const float2*>(h + (size_t)w * 128)[lane];
    float2 as2 = reinterpret_cast<const float2*>(a_src)[lane];
    float2 ad2 = reinterpret_cast<const float2*>(a_dst)[lane];
    float ps = hv.x * as2.x + hv.y * as2.y;
    float pd = hv.x * ad2.x + hv.y * ad2.y;
    #pragma unroll
    for (int off = 32; off; off >>= 1) {
        ps += __shfl_xor(ps, off);
        pd += __shfl_xor(pd, off);
    }
    if (lane == 0) { hs[w] = ps; hd[w] = pd; }
}

// ---------------- edge softmax + weighted aggregation ----------------

__global__ __launch_bounds__(256) void agg_kernel(const float* __restrict__ h,
                                                  const unsigned int* __restrict__ hb32,
                                                  const float* __restrict__ hs,
                                                  const float* __restrict__ hd,
                                                  const int* __restrict__ loptr,
                                                  const int* __restrict__ eiD,   // = ei + E (dst col)
                                                  const int* __restrict__ hiptr,
                                                  const int* __restrict__ csr,
                                                  const float* __restrict__ bias,
                                                  float* __restrict__ out,
                                                  unsigned int* __restrict__ outb,
                                                  int n) {
    __shared__ float esh[4][AGG_CAP];
    __shared__ int ush[4][AGG_CAP];
    int wib = threadIdx.x >> 6;
    int lane = threadIdx.x & 63;
    int v = blockIdx.x * 4 + wib;
    if (v >= n) return;   // grid exact (N % 4 == 0): never taken
    int s_lo = loptr[v];
    int dlo = loptr[v + 1] - s_lo;
    int s_hi = hiptr[v];
    int d = dlo + (hiptr[v + 1] - s_hi);
    float hdv = hd[v];
    float e_self = lrelu(hs[v] + hdv);
    float m, inv;
    bool fits = (d <= AGG_CAP);

    auto nbr = [&](int k) -> int {
        return (k < dlo) ? eiD[s_lo + k] : csr[s_hi + k - dlo];
    };
    auto gx = [&](int u) -> float2 {
        unsigned int w = hb32[(size_t)u * 64 + lane];
        return make_float2(__uint_as_float(w << 16), __uint_as_float(w & 0xFFFF0000u));
    };

    if (fits) {
        float mloc = -3.4e38f;
        for (int k = lane; k < d; k += 64) {
            int u = nbr(k);
            float e = lrelu(hs[u] + hdv);
            ush[wib][k] = u;
            esh[wib][k] = e;
            mloc = fmaxf(mloc, e);
        }
        #pragma unroll
        for (int off = 32; off; off >>= 1) mloc = fmaxf(mloc, __shfl_xor(mloc, off));
        m = fmaxf(mloc, e_self);
        float sloc = 0.f;
        for (int k = lane; k < d; k += 64) sloc += __expf(esh[wib][k] - m);
        #pragma unroll
        for (int off = 32; off; off >>= 1) sloc += __shfl_xor(sloc, off);
        float s = sloc + __expf(e_self - m);
        inv = 1.f / s;
        for (int k = lane; k < d; k += 64) esh[wib][k] = __expf(esh[wib][k] - m) * inv;
    } else {
        float mloc = -3.4e38f;
        for (int k = lane; k < d; k += 64) mloc = fmaxf(mloc, lrelu(hs[nbr(k)] + hdv));
        #pragma unroll
        for (int off = 32; off; off >>= 1) mloc = fmaxf(mloc, __shfl_xor(mloc, off));
        m = fmaxf(mloc, e_self);
        float sloc = 0.f;
        for (int k = lane; k < d; k += 64) sloc += __expf(lrelu(hs[nbr(k)] + hdv) - m);
        #pragma unroll
        for (int off = 32; off; off >>= 1) sloc += __shfl_xor(sloc, off);
        float s = sloc + __expf(e_self - m);
        inv = 1.f / s;
    }
    __syncthreads();   // make LDS alphas visible

    float2 hvv = reinterpret_cast<const float2*>(h + (size_t)v * 128)[lane];  // self row fp32
    float a_self = __expf(e_self - m) * inv;
    float accx = a_self * hvv.x;
    float accy = a_self * hvv.y;
    if (fits) {
        int k = 0;
        // unroll x8: 8 independent row-gathers in flight per lane
        for (; k + 8 <= d; k += 8) {
            float a_[8]; int u_[8]; float2 x_[8];
            #pragma unroll
            for (int j = 0; j < 8; ++j) { a_[j] = esh[wib][k + j]; u_[j] = ush[wib][k + j]; }
            #pragma unroll
            for (int j = 0; j < 8; ++j) x_[j] = gx(u_[j]);
            #pragma unroll
            for (int j = 0; j < 8; ++j) {
                accx = fmaf(a_[j], x_[j].x, accx);
                accy = fmaf(a_[j], x_[j].y, accy);
            }
        }
        for (; k < d; ++k) {
            float al = esh[wib][k];
            float2 xv = gx(ush[wib][k]);
            accx = fmaf(al, xv.x, accx);
            accy = fmaf(al, xv.y, accy);
        }
    } else {
        for (int k = 0; k < d; ++k) {
            int u = nbr(k);
            float al = __expf(lrelu(hs[u] + hdv) - m) * inv;
            float2 xv = gx(u);
            accx = fmaf(al, xv.x, accx);
            accy = fmaf(al, xv.y, accy);
        }
    }
    float2 bb = reinterpret_cast<const float2*>(bias)[lane];
    float o0 = selu(accx + bb.x);
    float o1 = selu(accy + bb.y);
    reinterpret_cast<float2*>(out + (size_t)v * 128)[lane] = make_float2(o0, o1);
    unsigned int pb = ((unsigned int)f2bf(o1) << 16) | (unsigned int)f2bf(o0);
    outb[(size_t)v * 64 + lane] = pb;
}

// ---------------- mean pool + MLP head ----------------

__device__ __forceinline__ int lower_bound_dev(const int* __restrict__ b, int n, int val) {
    int lo = 0, hi = n;
    while (lo < hi) {
        int mid = (lo + hi) >> 1;
        if (b[mid] < val) lo = mid + 1; else hi = mid;
    }
    return lo;
}

__global__ __launch_bounds__(1024) void pool_mlp_kernel(const float* __restrict__ h,
                                                        const int* __restrict__ batch,
                                                        const float* __restrict__ fw1,
                                                        const float* __restrict__ fb1,
                                                        const float* __restrict__ fw2,
                                                        const float* __restrict__ fb2,
                                                        float* __restrict__ out, int n) {
    int g = blockIdx.x;
    int t = threadIdx.x;
    int lane = t & 63;
    int rg = t >> 6;
    __shared__ float2 sm[16][64];
    __shared__ float gv[128];
    __shared__ float hid[64];
    __shared__ float logits[4];

    int s = lower_bound_dev(batch, n, g);
    int e = lower_bound_dev(batch, n, g + 1);

    float2 acc = make_float2(0.f, 0.f);
    const float2* h2 = reinterpret_cast<const float2*>(h);
    int i = s + rg;
    for (; i + 16 < e; i += 32) {
        float2 v0 = h2[(size_t)i * 64 + lane];
        float2 v1 = h2[(size_t)(i + 16) * 64 + lane];
        acc.x += v0.x + v1.x;
        acc.y += v0.y + v1.y;
    }
    for (; i < e; i += 16) {
        float2 v0 = h2[(size_t)i * 64 + lane];
        acc.x += v0.x;
        acc.y += v0.y;
    }
    sm[rg][lane] = acc;
    __syncthreads();
    if (rg == 0) {
        float2 tot = make_float2(0.f, 0.f);
        #pragma unroll
        for (int r = 0; r < 16; ++r) {
            tot.x += sm[r][lane].x;
            tot.y += sm[r][lane].y;
        }
        float cnt = fmaxf((float)(e - s), 1.0f);
        gv[lane * 2 + 0] = selu(tot.x / cnt);
        gv[lane * 2 + 1] = selu(tot.y / cnt);
    }
    __syncthreads();
    if (t < 64) {
        float a = fb1[t];
        for (int k = 0; k < 128; ++k) a = fmaf(fw1[t * 128 + k], gv[k], a);
        hid[t] = selu(a);
    }
    __syncthreads();
    if (t < 4) {
        float a = fb2[t];
        for (int k = 0; k < 64; ++k) a = fmaf(fw2[t * 64 + k], hid[k], a);
        logits[t] = a;
    }
    __syncthreads();
    if (t < 4) {
        float mx = fmaxf(fmaxf(logits[0], logits[1]), fmaxf(logits[2], logits[3]));
        float sum = __expf(logits[0] - mx) + __expf(logits[1] - mx) +
                    __expf(logits[2] - mx) + __expf(logits[3] - mx);
        out[g * 4 + t] = logits[t] - mx - logf(sum);
    }
}

// ---------------- launch ----------------

extern "C" void kernel_launch(void* const* d_in, const int* in_sizes, int n_in,
                              void* d_out, int out_size, void* d_ws, size_t ws_size,
                              hipStream_t stream) {
    const float* x   = (const float*)d_in[0];
    const int*   ei  = (const int*)d_in[1];
    const int*   bat = (const int*)d_in[2];
    const float* W1  = (const float*)d_in[3];
    const float* as1 = (const float*)d_in[4];
    const float* ad1 = (const float*)d_in[5];
    const float* b1  = (const float*)d_in[6];
    const float* W2  = (const float*)d_in[7];
    const float* as2 = (const float*)d_in[8];
    const float* ad2 = (const float*)d_in[9];
    const float* b2  = (const float*)d_in[10];
    const float* fw1 = (const float*)d_in[11];
    const float* fb1 = (const float*)d_in[12];
    const float* fw2 = (const float*)d_in[13];
    const float* fb2 = (const float*)d_in[14];
    float* out = (float*)d_out;

    char* ws = (char*)d_ws;
    size_t off = 0;
    auto alloc = [&](size_t bytes) {
        void* p = ws + off;
        off += (bytes + 255) & ~(size_t)255;
        return p;
    };
    float*          bufA    = (float*)alloc((size_t)NN * 128 * 4);  // GEMM output (h_lin)
    float*          bufB    = (float*)alloc((size_t)NN * 128 * 4);  // conv output (post selu)
    unsigned short* hb      = (unsigned short*)alloc((size_t)NN * 128 * 2);  // bf16 shadow of h_lin
    unsigned short* hbB     = (unsigned short*)alloc((size_t)NN * 128 * 2);  // bf16 shadow of conv out
    unsigned short* wb1     = (unsigned short*)alloc((size_t)HID * 256 * 2); // bf16 W1
    unsigned short* wb2     = (unsigned short*)alloc((size_t)HID * 128 * 2); // bf16 W2
    float*          hs      = (float*)alloc((size_t)NN * 4);
    float*          hd      = (float*)alloc((size_t)NN * 4);
    int*            deg     = (int*)alloc((size_t)NN * 4);
    int*            row_ptr = (int*)alloc((size_t)(NN + 1) * 4);    // hi-side CSR rows
    int*            cursor  = (int*)alloc((size_t)NN * 4);
    int*            loptr   = (int*)alloc((size_t)(NN + 1) * 4);    // lo-side row starts
    int*            csr     = (int*)alloc((size_t)EE * 4);          // hi-side only
    uint2*          tmp     = (uint2*)alloc((size_t)EE * 8);        // bucketed (u,v) pairs
    int*            bcur    = (int*)alloc((size_t)NBKT * 4);
    int*            bsum    = (int*)alloc(256 * 4);
    int*            boff    = (int*)alloc(256 * 4);

    // ---- adjacency build ----
    hipMemsetAsync(deg, 0, (size_t)NN * 4, stream);
    loptr_kernel<<<(NN + 1 + 255) / 256, 256, 0, stream>>>(ei, loptr, NN, EE);
    count_kernel<<<(EE + 255) / 256, 256, 0, stream>>>(ei, deg, EE);
    int NB = (NN + SCAN_CHUNK - 1) / SCAN_CHUNK;   // 196
    block_sum_kernel<<<NB, 256, 0, stream>>>(deg, bsum, NN);
    top_scan_kernel<<<1, 256, 0, stream>>>(bsum, boff, NB, row_ptr + NN);
    scan_final_kernel<<<NB, 512, 0, stream>>>(deg, boff, row_ptr, cursor, NN);
    bcur_init_kernel<<<(NBKT + 255) / 256, 256, 0, stream>>>(row_ptr, bcur);
    binA_kernel<<<(EE + 255) / 256, 256, 0, stream>>>(ei, bcur, tmp, EE);
    binB_kernel<<<(EE + 255) / 256, 256, 0, stream>>>(tmp, cursor, csr, EE);

    // ---- weight casts ----
    castbf_kernel<<<(HID * 256 / 4 + 255) / 256, 256, 0, stream>>>(W1, wb1, HID * 256);
    castbf_kernel<<<(HID * 128 / 4 + 255) / 256, 256, 0, stream>>>(W2, wb2, HID * 128);

    const int* eiD = ei + EE;   // dst (hi) column
    int gemmGrid = (NN + 127) / 128;   // 782

    // ---- GAT layer 1 ----
    mfma_gemm<256, false><<<gemmGrid, 256, 0, stream>>>(x, wb1, bufA, hb, NN);
    hshd_kernel<<<((size_t)NN * 64 + 255) / 256, 256, 0, stream>>>(bufA, as1, ad1, hs, hd, NN);
    agg_kernel<<<(NN + 3) / 4, 256, 0, stream>>>(bufA, (const unsigned int*)hb, hs, hd,
                                                 loptr, eiD, row_ptr, csr, b1, bufB,
                                                 (unsigned int*)hbB, NN);

    // ---- GAT layer 2 ----
    mfma_gemm<128, true><<<gemmGrid, 256, 0, stream>>>(hbB, wb2, bufA, hb, NN);
    hshd_kernel<<<((size_t)NN * 64 + 255) / 256, 256, 0, stream>>>(bufA, as2, ad2, hs, hd, NN);
    agg_kernel<<<(NN + 3) / 4, 256, 0, stream>>>(bufA, (const unsigned int*)hb, hs, hd,
                                                 loptr, eiD, row_ptr, csr, b2, bufB,
                                                 (unsigned int*)hbB, NN);

    // ---- pool + MLP + log_softmax ----
    pool_mlp_kernel<<<GG, 1024, 0, stream>>>(bufB, bat, fw1, fb1, fw2, fb2, out, NN);
}

// Round 7
// 682.938 us; speedup vs baseline: 1.6845x; 1.6845x over previous
//
#include <hip/hip_runtime.h>
#include <hip/hip_bf16.h>

// ---------------------------------------------------------------------------
// GCNFN: 2x GATConv(heads=1) + SELU, global mean pool, MLP head, log_softmax
// N=100000 nodes, E=1600000 canonical edges (expanded to 2E directed + N self)
//
// R1: lo-side adjacency from sorted edge list (binary search); hi-side CSR.
// R2: bf16 shadow of h for the agg gather (halves gather bytes).
// R3: pool_mlp 1024-thread parallel reduction (was 2.6% occupancy).
// R4: bf16 MFMA GEMM (16x16x32, fp32 accum) replaces fp32 VALU SGEMM.
// R5 FAILED: 782-bucket scatter = 2046 serialized atomics/address = 492us.
//     Reverted to direct per-node cursor scatter (100k addresses, 130us).
// R6: all-bf16 dataflow. hs/hd fused into GEMM epilogue (hshd kernels gone);
//     GEMM writes bf16 shadow only (no fp32 C); agg reads/writes bf16 only;
//     pool reads bf16. Removes ~330MB of fp32 intermediate traffic.
// ---------------------------------------------------------------------------

#define NN 100000
#define EE 1600000
#define GG 128
#define HID 128
#define AGG_CAP 512
#define NEG_SLOPE 0.2f

typedef short bf16x8 __attribute__((ext_vector_type(8)));
typedef float f32x4 __attribute__((ext_vector_type(4)));

__device__ __forceinline__ float lrelu(float x) { return x > 0.f ? x : NEG_SLOPE * x; }

__device__ __forceinline__ float selu(float x) {
    const float sc = 1.0507009873554805f, al = 1.6732632423543772f;
    return x > 0.f ? sc * x : sc * al * (__expf(x) - 1.f);
}

__device__ __forceinline__ unsigned short f2bf(float x) {
    unsigned int b = __float_as_uint(x);
    b += 0x7FFFu + ((b >> 16) & 1u);          // round-to-nearest-even
    return (unsigned short)(b >> 16);
}

// ---------------- fp32 -> bf16 cast (weights) ----------------

__global__ __launch_bounds__(256) void castbf_kernel(const float* __restrict__ in,
                                                     unsigned short* __restrict__ out, int n) {
    int i = (blockIdx.x * blockDim.x + threadIdx.x) * 4;
    if (i >= n) return;
    float4 v = *reinterpret_cast<const float4*>(in + i);
    union { unsigned short u[4]; uint2 w; } pk;
    pk.u[0] = f2bf(v.x); pk.u[1] = f2bf(v.y); pk.u[2] = f2bf(v.z); pk.u[3] = f2bf(v.w);
    *reinterpret_cast<uint2*>(out + i) = pk.w;
}

// ---------------- lo-side row starts: binary search over sorted lo column ----

__global__ __launch_bounds__(256) void loptr_kernel(const int* __restrict__ ei,
                                                    int* __restrict__ loptr, int n, int E_) {
    int v = blockIdx.x * blockDim.x + threadIdx.x;
    if (v > n) return;
    int lo = 0, hi = E_;
    while (lo < hi) {
        int mid = (lo + hi) >> 1;
        if (ei[mid] < v) lo = mid + 1; else hi = mid;
    }
    loptr[v] = lo;
}

// ---------------- hi-side CSR build ----------------

__global__ void count_kernel(const int* __restrict__ ei, int* __restrict__ deg, int E_) {
    int e = blockIdx.x * blockDim.x + threadIdx.x;
    if (e >= E_) return;
    atomicAdd(&deg[ei[E_ + e]], 1);   // hi endpoint only
}

#define SCAN_CHUNK 512

__global__ __launch_bounds__(256) void block_sum_kernel(const int* __restrict__ deg,
                                                        int* __restrict__ bsum, int n) {
    __shared__ int sd[256];
    int b = blockIdx.x, t = threadIdx.x;
    int base = b * SCAN_CHUNK;
    int v = 0;
    int i0 = base + t, i1 = base + t + 256;
    if (i0 < n) v += deg[i0];
    if (i1 < n) v += deg[i1];
    sd[t] = v;
    __syncthreads();
    for (int off = 128; off; off >>= 1) {
        if (t < off) sd[t] += sd[t + off];
        __syncthreads();
    }
    if (t == 0) bsum[b] = sd[0];
}

__global__ __launch_bounds__(256) void top_scan_kernel(const int* __restrict__ bsum,
                                                       int* __restrict__ boff, int nb,
                                                       int* __restrict__ total_out) {
    __shared__ int a[256], b[256];
    int t = threadIdx.x;
    int v = (t < nb) ? bsum[t] : 0;
    int* cur = a; int* nxt = b;
    cur[t] = v;
    __syncthreads();
    for (int off = 1; off < 256; off <<= 1) {
        int val = cur[t] + ((t >= off) ? cur[t - off] : 0);
        nxt[t] = val;
        __syncthreads();
        int* tmp = cur; cur = nxt; nxt = tmp;
    }
    if (t < nb) boff[t] = cur[t] - v;            // exclusive offset per block
    if (t == nb - 1) *total_out = cur[t];        // row_ptr[N] = E
}

__global__ __launch_bounds__(512) void scan_final_kernel(const int* __restrict__ deg,
                                                         const int* __restrict__ boff,
                                                         int* __restrict__ row_ptr,
                                                         int* __restrict__ cursor, int n) {
    __shared__ int a[512], b[512];
    int blk = blockIdx.x, t = threadIdx.x;
    int i = blk * 512 + t;
    int v = (i < n) ? deg[i] : 0;
    int orig = v;
    int* cur = a; int* nxt = b;
    cur[t] = v;
    __syncthreads();
    for (int off = 1; off < 512; off <<= 1) {
        int val = cur[t] + ((t >= off) ? cur[t - off] : 0);
        nxt[t] = val;
        __syncthreads();
        int* tmp = cur; cur = nxt; nxt = tmp;
    }
    if (i < n) {
        int excl = cur[t] - orig + boff[blk];
        row_ptr[i] = excl;
        cursor[i] = excl;
    }
}

// direct per-node cursor scatter (R4-proven; 100k counters, ~32 atomics each)
__global__ void scatter_kernel(const int* __restrict__ ei, int* __restrict__ cursor,
                               int* __restrict__ csr, int E_) {
    int e = blockIdx.x * blockDim.x + threadIdx.x;
    if (e >= E_) return;
    int u = ei[e], v = ei[E_ + e];
    int p = atomicAdd(&cursor[v], 1);   // hi side only
    csr[p] = u;
}

// ---------------- MFMA GEMM: Cb[M][128] = bf16(A[M][K] @ W[128][K]^T) ------
// BM=128, BN=128, BK=32; 256 threads = 4 waves (2x2), each wave 64x64 out.
// Epilogue fuses hs = h . a_src, hd = h . a_dst (per-row dot products):
//  per-thread partial over its 4 cols -> 16-lane shfl reduce -> LDS combine.

template<int K, bool BF16IN>
__global__ __launch_bounds__(256) void mfma_gemm(const void* __restrict__ Ain,
                                                 const unsigned short* __restrict__ Wb,
                                                 const float* __restrict__ avs,
                                                 const float* __restrict__ avd,
                                                 unsigned short* __restrict__ Cb,
                                                 float* __restrict__ hs,
                                                 float* __restrict__ hd,
                                                 int M) {
    __shared__ unsigned short As[128 * 32];
    __shared__ unsigned short Bs[128 * 32];
    __shared__ float hsp[128][2];
    __shared__ float hdp[128][2];
    int tid = threadIdx.x;
    int brow = blockIdx.x * 128;
    int w = tid >> 6, lane = tid & 63;
    int wr = (w >> 1) * 64, wc = (w & 1) * 64;
    int whalf = w & 1;
    int l15 = lane & 15, g = lane >> 4;

    const f32x4 zero = {0.f, 0.f, 0.f, 0.f};
    f32x4 acc[4][4];
    #pragma unroll
    for (int m = 0; m < 4; ++m)
        #pragma unroll
        for (int n = 0; n < 4; ++n) acc[m][n] = zero;

    int srow = tid >> 2;        // 0..63
    int slot = tid & 3;         // 16B slot within 64B row

    for (int k0 = 0; k0 < K; k0 += 32) {
        #pragma unroll
        for (int half = 0; half < 2; ++half) {
            int r = srow + half * 64;
            int grow = brow + r;
            union { unsigned short u[8]; uint4 v; } pk;
            if (BF16IN) {
                const unsigned short* A16 = (const unsigned short*)Ain;
                if (grow < M)
                    pk.v = *reinterpret_cast<const uint4*>(A16 + (size_t)grow * K + k0 + slot * 8);
                else pk.v = make_uint4(0, 0, 0, 0);
            } else {
                const float* A32 = (const float*)Ain;
                if (grow < M) {
                    const float4* p = reinterpret_cast<const float4*>(A32 + (size_t)grow * K + k0 + slot * 8);
                    float4 f0 = p[0], f1 = p[1];
                    pk.u[0] = f2bf(f0.x); pk.u[1] = f2bf(f0.y);
                    pk.u[2] = f2bf(f0.z); pk.u[3] = f2bf(f0.w);
                    pk.u[4] = f2bf(f1.x); pk.u[5] = f2bf(f1.y);
                    pk.u[6] = f2bf(f1.z); pk.u[7] = f2bf(f1.w);
                } else pk.v = make_uint4(0, 0, 0, 0);
            }
            int ss = slot ^ (r & 3);
            *reinterpret_cast<uint4*>(&As[r * 32 + ss * 8]) = pk.v;
        }
        #pragma unroll
        for (int half = 0; half < 2; ++half) {
            int r = srow + half * 64;
            uint4 v = *reinterpret_cast<const uint4*>(Wb + (size_t)r * K + k0 + slot * 8);
            int ss = slot ^ (r & 3);
            *reinterpret_cast<uint4*>(&Bs[r * 32 + ss * 8]) = v;
        }
        __syncthreads();

        bf16x8 af[4], bfr[4];
        #pragma unroll
        for (int m = 0; m < 4; ++m) {
            int row = wr + m * 16 + l15;
            af[m] = *reinterpret_cast<const bf16x8*>(&As[row * 32 + ((g ^ (row & 3)) * 8)]);
        }
        #pragma unroll
        for (int n = 0; n < 4; ++n) {
            int col = wc + n * 16 + l15;
            bfr[n] = *reinterpret_cast<const bf16x8*>(&Bs[col * 32 + ((g ^ (col & 3)) * 8)]);
        }
        #pragma unroll
        for (int m = 0; m < 4; ++m)
            #pragma unroll
            for (int n = 0; n < 4; ++n)
                acc[m][n] = __builtin_amdgcn_mfma_f32_16x16x32_bf16(af[m], bfr[n], acc[m][n], 0, 0, 0);
        __syncthreads();
    }

    // ---- epilogue 1: bf16 shadow write ----
    #pragma unroll
    for (int m = 0; m < 4; ++m) {
        int rbase = brow + wr + m * 16 + g * 4;
        #pragma unroll
        for (int j = 0; j < 4; ++j) {
            int row = rbase + j;
            if (row < M) {
                #pragma unroll
                for (int n = 0; n < 4; ++n) {
                    int col = wc + n * 16 + l15;
                    Cb[(size_t)row * 128 + col] = f2bf(acc[m][n][j]);
                }
            }
        }
    }

    // ---- epilogue 2: fused hs/hd row dots ----
    float asv[4], adv[4];
    #pragma unroll
    for (int n = 0; n < 4; ++n) {
        asv[n] = avs[wc + n * 16 + l15];
        adv[n] = avd[wc + n * 16 + l15];
    }
    #pragma unroll
    for (int m = 0; m < 4; ++m) {
        #pragma unroll
        for (int j = 0; j < 4; ++j) {
            float vs = 0.f, vd = 0.f;
            #pragma unroll
            for (int n = 0; n < 4; ++n) {
                float a = acc[m][n][j];
                vs = fmaf(a, asv[n], vs);
                vd = fmaf(a, adv[n], vd);
            }
            #pragma unroll
            for (int off = 1; off < 16; off <<= 1) {
                vs += __shfl_xor(vs, off);
                vd += __shfl_xor(vd, off);
            }
            if (l15 == 0) {
                int rl = wr + m * 16 + g * 4 + j;
                hsp[rl][whalf] = vs;
                hdp[rl][whalf] = vd;
            }
        }
    }
    __syncthreads();
    if (tid < 128) {
        int row = brow + tid;
        if (row < M) {
            hs[row] = hsp[tid][0] + hsp[tid][1];
            hd[row] = hdp[tid][0] + hdp[tid][1];
        }
    }
}

// ---------------- edge softmax + weighted aggregation (all-bf16 I/O) -------

__global__ __launch_bounds__(256) void agg_kernel(const unsigned int* __restrict__ hb32,
                                                  const float* __restrict__ hs,
                                                  const float* __restrict__ hd,
                                                  const int* __restrict__ loptr,
                                                  const int* __restrict__ eiD,   // = ei + E (dst col)
                                                  const int* __restrict__ hiptr,
                                                  const int* __restrict__ csr,
                                                  const float* __restrict__ bias,
                                                  unsigned int* __restrict__ outb,
                                                  int n) {
    __shared__ float esh[4][AGG_CAP];
    __shared__ int ush[4][AGG_CAP];
    int wib = threadIdx.x >> 6;
    int lane = threadIdx.x & 63;
    int v = blockIdx.x * 4 + wib;
    if (v >= n) return;   // grid exact (N % 4 == 0): never taken
    int s_lo = loptr[v];
    int dlo = loptr[v + 1] - s_lo;
    int s_hi = hiptr[v];
    int d = dlo + (hiptr[v + 1] - s_hi);
    float hdv = hd[v];
    float e_self = lrelu(hs[v] + hdv);
    float m, inv;
    bool fits = (d <= AGG_CAP);

    auto nbr = [&](int k) -> int {
        return (k < dlo) ? eiD[s_lo + k] : csr[s_hi + k - dlo];
    };
    auto gx = [&](int u) -> float2 {
        unsigned int w = hb32[(size_t)u * 64 + lane];
        return make_float2(__uint_as_float(w << 16), __uint_as_float(w & 0xFFFF0000u));
    };

    if (fits) {
        float mloc = -3.4e38f;
        for (int k = lane; k < d; k += 64) {
            int u = nbr(k);
            float e = lrelu(hs[u] + hdv);
            ush[wib][k] = u;
            esh[wib][k] = e;
            mloc = fmaxf(mloc, e);
        }
        #pragma unroll
        for (int off = 32; off; off >>= 1) mloc = fmaxf(mloc, __shfl_xor(mloc, off));
        m = fmaxf(mloc, e_self);
        float sloc = 0.f;
        for (int k = lane; k < d; k += 64) sloc += __expf(esh[wib][k] - m);
        #pragma unroll
        for (int off = 32; off; off >>= 1) sloc += __shfl_xor(sloc, off);
        float s = sloc + __expf(e_self - m);
        inv = 1.f / s;
        for (int k = lane; k < d; k += 64) esh[wib][k] = __expf(esh[wib][k] - m) * inv;
    } else {
        float mloc = -3.4e38f;
        for (int k = lane; k < d; k += 64) mloc = fmaxf(mloc, lrelu(hs[nbr(k)] + hdv));
        #pragma unroll
        for (int off = 32; off; off >>= 1) mloc = fmaxf(mloc, __shfl_xor(mloc, off));
        m = fmaxf(mloc, e_self);
        float sloc = 0.f;
        for (int k = lane; k < d; k += 64) sloc += __expf(lrelu(hs[nbr(k)] + hdv) - m);
        #pragma unroll
        for (int off = 32; off; off >>= 1) sloc += __shfl_xor(sloc, off);
        float s = sloc + __expf(e_self - m);
        inv = 1.f / s;
    }
    __syncthreads();   // make LDS alphas visible

    float2 hvv = gx(v);                       // self row (bf16 shadow)
    float a_self = __expf(e_self - m) * inv;
    float accx = a_self * hvv.x;
    float accy = a_self * hvv.y;
    if (fits) {
        int k = 0;
        // unroll x8: 8 independent row-gathers in flight per lane
        for (; k + 8 <= d; k += 8) {
            float a_[8]; int u_[8]; float2 x_[8];
            #pragma unroll
            for (int j = 0; j < 8; ++j) { a_[j] = esh[wib][k + j]; u_[j] = ush[wib][k + j]; }
            #pragma unroll
            for (int j = 0; j < 8; ++j) x_[j] = gx(u_[j]);
            #pragma unroll
            for (int j = 0; j < 8; ++j) {
                accx = fmaf(a_[j], x_[j].x, accx);
                accy = fmaf(a_[j], x_[j].y, accy);
            }
        }
        for (; k < d; ++k) {
            float al = esh[wib][k];
            float2 xv = gx(ush[wib][k]);
            accx = fmaf(al, xv.x, accx);
            accy = fmaf(al, xv.y, accy);
        }
    } else {
        for (int k = 0; k < d; ++k) {
            int u = nbr(k);
            float al = __expf(lrelu(hs[u] + hdv) - m) * inv;
            float2 xv = gx(u);
            accx = fmaf(al, xv.x, accx);
            accy = fmaf(al, xv.y, accy);
        }
    }
    float2 bb = reinterpret_cast<const float2*>(bias)[lane];
    float o0 = selu(accx + bb.x);
    float o1 = selu(accy + bb.y);
    unsigned int pb = ((unsigned int)f2bf(o1) << 16) | (unsigned int)f2bf(o0);
    outb[(size_t)v * 64 + lane] = pb;
}

// ---------------- mean pool (bf16 input) + MLP head ----------------

__device__ __forceinline__ int lower_bound_dev(const int* __restrict__ b, int n, int val) {
    int lo = 0, hi = n;
    while (lo < hi) {
        int mid = (lo + hi) >> 1;
        if (b[mid] < val) lo = mid + 1; else hi = mid;
    }
    return lo;
}

__global__ __launch_bounds__(1024) void pool_mlp_kernel(const unsigned int* __restrict__ hb,
                                                        const int* __restrict__ batch,
                                                        const float* __restrict__ fw1,
                                                        const float* __restrict__ fb1,
                                                        const float* __restrict__ fw2,
                                                        const float* __restrict__ fb2,
                                                        float* __restrict__ out, int n) {
    int g = blockIdx.x;
    int t = threadIdx.x;
    int lane = t & 63;
    int rg = t >> 6;
    __shared__ float2 sm[16][64];
    __shared__ float gv[128];
    __shared__ float hid[64];
    __shared__ float logits[4];

    int s = lower_bound_dev(batch, n, g);
    int e = lower_bound_dev(batch, n, g + 1);

    float2 acc = make_float2(0.f, 0.f);
    int i = s + rg;
    for (; i + 16 < e; i += 32) {
        unsigned int w0 = hb[(size_t)i * 64 + lane];
        unsigned int w1 = hb[(size_t)(i + 16) * 64 + lane];
        acc.x += __uint_as_float(w0 << 16) + __uint_as_float(w1 << 16);
        acc.y += __uint_as_float(w0 & 0xFFFF0000u) + __uint_as_float(w1 & 0xFFFF0000u);
    }
    for (; i < e; i += 16) {
        unsigned int w0 = hb[(size_t)i * 64 + lane];
        acc.x += __uint_as_float(w0 << 16);
        acc.y += __uint_as_float(w0 & 0xFFFF0000u);
    }
    sm[rg][lane] = acc;
    __syncthreads();
    if (rg == 0) {
        float2 tot = make_float2(0.f, 0.f);
        #pragma unroll
        for (int r = 0; r < 16; ++r) {
            tot.x += sm[r][lane].x;
            tot.y += sm[r][lane].y;
        }
        float cnt = fmaxf((float)(e - s), 1.0f);
        gv[lane * 2 + 0] = selu(tot.x / cnt);
        gv[lane * 2 + 1] = selu(tot.y / cnt);
    }
    __syncthreads();
    if (t < 64) {
        float a = fb1[t];
        for (int k = 0; k < 128; ++k) a = fmaf(fw1[t * 128 + k], gv[k], a);
        hid[t] = selu(a);
    }
    __syncthreads();
    if (t < 4) {
        float a = fb2[t];
        for (int k = 0; k < 64; ++k) a = fmaf(fw2[t * 64 + k], hid[k], a);
        logits[t] = a;
    }
    __syncthreads();
    if (t < 4) {
        float mx = fmaxf(fmaxf(logits[0], logits[1]), fmaxf(logits[2], logits[3]));
        float sum = __expf(logits[0] - mx) + __expf(logits[1] - mx) +
                    __expf(logits[2] - mx) + __expf(logits[3] - mx);
        out[g * 4 + t] = logits[t] - mx - logf(sum);
    }
}

// ---------------- launch ----------------

extern "C" void kernel_launch(void* const* d_in, const int* in_sizes, int n_in,
                              void* d_out, int out_size, void* d_ws, size_t ws_size,
                              hipStream_t stream) {
    const float* x   = (const float*)d_in[0];
    const int*   ei  = (const int*)d_in[1];
    const int*   bat = (const int*)d_in[2];
    const float* W1  = (const float*)d_in[3];
    const float* as1 = (const float*)d_in[4];
    const float* ad1 = (const float*)d_in[5];
    const float* b1  = (const float*)d_in[6];
    const float* W2  = (const float*)d_in[7];
    const float* as2 = (const float*)d_in[8];
    const float* ad2 = (const float*)d_in[9];
    const float* b2  = (const float*)d_in[10];
    const float* fw1 = (const float*)d_in[11];
    const float* fb1 = (const float*)d_in[12];
    const float* fw2 = (const float*)d_in[13];
    const float* fb2 = (const float*)d_in[14];
    float* out = (float*)d_out;

    char* ws = (char*)d_ws;
    size_t off = 0;
    auto alloc = [&](size_t bytes) {
        void* p = ws + off;
        off += (bytes + 255) & ~(size_t)255;
        return p;
    };
    unsigned short* hb      = (unsigned short*)alloc((size_t)NN * 128 * 2);  // bf16 h_lin (GEMM out)
    unsigned short* hbB     = (unsigned short*)alloc((size_t)NN * 128 * 2);  // bf16 conv out
    unsigned short* wb1     = (unsigned short*)alloc((size_t)HID * 256 * 2); // bf16 W1
    unsigned short* wb2     = (unsigned short*)alloc((size_t)HID * 128 * 2); // bf16 W2
    float*          hs      = (float*)alloc((size_t)NN * 4);
    float*          hd      = (float*)alloc((size_t)NN * 4);
    int*            deg     = (int*)alloc((size_t)NN * 4);
    int*            row_ptr = (int*)alloc((size_t)(NN + 1) * 4);    // hi-side CSR rows
    int*            cursor  = (int*)alloc((size_t)NN * 4);
    int*            loptr   = (int*)alloc((size_t)(NN + 1) * 4);    // lo-side row starts
    int*            csr     = (int*)alloc((size_t)EE * 4);          // hi-side only
    int*            bsum    = (int*)alloc(256 * 4);
    int*            boff    = (int*)alloc(256 * 4);

    // ---- adjacency build ----
    hipMemsetAsync(deg, 0, (size_t)NN * 4, stream);
    loptr_kernel<<<(NN + 1 + 255) / 256, 256, 0, stream>>>(ei, loptr, NN, EE);
    count_kernel<<<(EE + 255) / 256, 256, 0, stream>>>(ei, deg, EE);
    int NB = (NN + SCAN_CHUNK - 1) / SCAN_CHUNK;   // 196
    block_sum_kernel<<<NB, 256, 0, stream>>>(deg, bsum, NN);
    top_scan_kernel<<<1, 256, 0, stream>>>(bsum, boff, NB, row_ptr + NN);
    scan_final_kernel<<<NB, 512, 0, stream>>>(deg, boff, row_ptr, cursor, NN);
    scatter_kernel<<<(EE + 255) / 256, 256, 0, stream>>>(ei, cursor, csr, EE);

    // ---- weight casts ----
    castbf_kernel<<<(HID * 256 / 4 + 255) / 256, 256, 0, stream>>>(W1, wb1, HID * 256);
    castbf_kernel<<<(HID * 128 / 4 + 255) / 256, 256, 0, stream>>>(W2, wb2, HID * 128);

    const int* eiD = ei + EE;   // dst (hi) column
    int gemmGrid = (NN + 127) / 128;   // 782

    // ---- GAT layer 1 ----
    mfma_gemm<256, false><<<gemmGrid, 256, 0, stream>>>(x, wb1, as1, ad1, hb, hs, hd, NN);
    agg_kernel<<<(NN + 3) / 4, 256, 0, stream>>>((const unsigned int*)hb, hs, hd,
                                                 loptr, eiD, row_ptr, csr, b1,
                                                 (unsigned int*)hbB, NN);

    // ---- GAT layer 2 ----
    mfma_gemm<128, true><<<gemmGrid, 256, 0, stream>>>(hbB, wb2, as2, ad2, hb, hs, hd, NN);
    agg_kernel<<<(NN + 3) / 4, 256, 0, stream>>>((const unsigned int*)hb, hs, hd,
                                                 loptr, eiD, row_ptr, csr, b2,
                                                 (unsigned int*)hbB, NN);

    // ---- pool + MLP + log_softmax ----
    pool_mlp_kernel<<<GG, 1024, 0, stream>>>((const unsigned int*)hbB, bat,
                                             fw1, fb1, fw2, fb2, out, NN);
}